// Round 7
// baseline (355.731 us; speedup 1.0000x reference)
//
#include <hip/hip_runtime.h>
#include <hip/hip_bf16.h>

#define TOK 4096
#define DIM 1024
#define HID 2048
#define LN10K 9.210340371976184f

typedef __bf16 bh;
typedef __bf16 v8bf __attribute__((ext_vector_type(8)));
typedef float v16f __attribute__((ext_vector_type(16)));

typedef const __attribute__((address_space(1))) void* gvp;
typedef __attribute__((address_space(3))) void* svp;

__device__ __forceinline__ void gl_lds16(const bh* g, bh* s) {
  __builtin_amdgcn_global_load_lds((gvp)g, (svp)s, 16, 0, 0);
}

// ---------------- prep: cast X -> feat left half, colsum(E) ----------------
__global__ __launch_bounds__(256) void prep_x_colsum(const float* __restrict__ X,
                                                     bh* __restrict__ featb,
                                                     float* __restrict__ S) {
  int cp = blockIdx.x * 256 + threadIdx.x;      // column pair 0..511
  int c = cp * 2;
  int r0 = blockIdx.y * 16;
  float inv_denom = __expf(-(float)c * (LN10K / (float)DIM));
  float s0 = 0.f, s1 = 0.f;
#pragma unroll 4
  for (int r = r0; r < r0 + 16; ++r) {
    float2 x = *(const float2*)(X + (size_t)r * DIM + c);
    float sn, cs;
    __sincosf((float)r * inv_denom, &sn, &cs);
    s0 += sn * x.x;
    s1 += cs * x.y;
    bh pair[2] = {(bh)x.x, (bh)x.y};
    *(ushort2*)(featb + (size_t)r * (2 * DIM) + c) = *(ushort2*)pair;
  }
  atomicAdd(&S[c], s0);
  atomicAdd(&S[c + 1], s1);
}

// ---------------- prep: loo -> feat right half ----------------
__global__ __launch_bounds__(256) void prep_loo(const float* __restrict__ X,
                                                const float* __restrict__ S,
                                                bh* __restrict__ featb) {
  size_t e4 = ((size_t)blockIdx.x * 256 + threadIdx.x) * 4;  // over TOK*DIM
  int r = (int)(e4 >> 10);
  int c = (int)(e4 & 1023);
  float4 x = *(const float4*)(X + e4);
  float4 s = *(const float4*)(S + c);
  float id0 = __expf(-(float)c * (LN10K / (float)DIM));
  float id1 = __expf(-(float)(c + 2) * (LN10K / (float)DIM));
  float sn0, cs0, sn1, cs1;
  __sincosf((float)r * id0, &sn0, &cs0);
  __sincosf((float)r * id1, &sn1, &cs1);
  const float inv = 1.0f / (float)(TOK - 1);
  bh outv[4];
  outv[0] = (bh)((s.x - sn0 * x.x) * inv);
  outv[1] = (bh)((s.y - cs0 * x.y) * inv);
  outv[2] = (bh)((s.z - sn1 * x.z) * inv);
  outv[3] = (bh)((s.w - cs1 * x.w) * inv);
  *(ushort4*)(featb + (size_t)r * (2 * DIM) + DIM + c) = *(ushort4*)outv;
}

// ---------------- fused transpose+cast of all 3 weights (1 dispatch) -------
__global__ __launch_bounds__(256) void transpose_all(const float* __restrict__ Wv,
                                                     const float* __restrict__ W1,
                                                     const float* __restrict__ W2,
                                                     bh* __restrict__ WvT,
                                                     bh* __restrict__ W1T,
                                                     bh* __restrict__ W2T) {
  __shared__ float tile[32][33];
  int bid = blockIdx.x;
  const float* in; bh* out; int Ncol, R, bx, by;
  if (bid < 1024)      { in = Wv; out = WvT; Ncol = DIM; R = DIM;
                         bx = bid & 31; by = bid >> 5; }
  else if (bid < 5120) { int b = bid - 1024; in = W1; out = W1T; Ncol = HID; R = 2 * DIM;
                         bx = b & 63; by = b >> 6; }
  else                 { int b = bid - 5120; in = W2; out = W2T; Ncol = TOK; R = HID;
                         bx = b & 127; by = b >> 7; }
  int nb = bx * 32, rb = by * 32;
  int tx = threadIdx.x, ty = threadIdx.y;  // block (32,8)
#pragma unroll
  for (int j = 0; j < 32; j += 8)
    tile[ty + j][tx] = in[(size_t)(rb + ty + j) * Ncol + nb + tx];
  __syncthreads();
#pragma unroll
  for (int j = 0; j < 32; j += 8)
    out[(size_t)(nb + ty + j) * R + rb + tx] = (bh)tile[tx][ty + j];
}

// ---------------- GEMM: C = act(A @ BT^T + bias), 32x32x16 MFMA ------------
// A: M x K row-major bf16 (lda). BT: N x K row-major bf16 (B^T).
// 128-thread blocks (2 waves), block tile 128 x BN, BK=64, wave tile 64 x BN
// as 2 x (BN/32) tiles of 32x32x16 (fewer matrix-pipe cyc/FLOP than 16x16x32:
// 8.07 vs 2x4.85, m119; same LDS fragment bytes).
// A/B operand: m|n = lane&31, k = (lane>>5)*8 + j.
// C/D (m74/m101): col = lane&31, row = (reg&3) + 8*(reg>>2) + 4*(lane>>5).
// Staging: global_load_lds w=16, lane-linear LDS, 16B-grain XOR swizzle row&7.
template <int BN, bool RELU, bool TROUT, typename OutT>
__global__ __launch_bounds__(128, 2) void gemm_bt(const bh* __restrict__ A,
                                                  const bh* __restrict__ BT,
                                                  const float* __restrict__ bias,
                                                  OutT* __restrict__ C,
                                                  int K, int lda, int ldbt, int ldc) {
  constexpr int NT = BN / 32;          // 4 (BN=128) or 2 (BN=64)
  __shared__ bh As[128 * 64];          // 16 KB
  __shared__ bh Bs[BN * 64];           // 16 or 8 KB
  const int t = threadIdx.x;
  const int bm = blockIdx.y * 128, bn = blockIdx.x * BN;

  const int sr = t >> 3;               // staging row-in-group
  const int c8 = ((t & 7) ^ (sr & 7)) * 8;
  const bh* gA = A + (size_t)(bm + sr) * lda + c8;
  const bh* gB = BT + (size_t)(bn + sr) * ldbt + c8;
  bh* sA = As + t * 8;
  bh* sB = Bs + t * 8;

  const int lane = t & 63, w = t >> 6;
  const int l31 = lane & 31, kc = lane >> 5;   // kc in {0,1}

  v16f acc[2][NT] = {};
  for (int k0 = 0; k0 < K; k0 += 64) {
#pragma unroll
    for (int j = 0; j < 8; ++j)
      gl_lds16(gA + k0 + j * 16 * lda, sA + j * 1024);
#pragma unroll
    for (int j = 0; j < BN / 16; ++j)
      gl_lds16(gB + k0 + j * 16 * ldbt, sB + j * 1024);
    __syncthreads();
#pragma unroll
    for (int ks = 0; ks < 4; ++ks) {           // K16 steps within K64
      const int off = ((ks * 2 + kc) ^ (l31 & 7)) * 8;
      v8bf af[2], bfr[NT];
#pragma unroll
      for (int mt = 0; mt < 2; ++mt)
        af[mt] = *(const v8bf*)(As + (w * 64 + mt * 32 + l31) * 64 + off);
#pragma unroll
      for (int nt = 0; nt < NT; ++nt)
        bfr[nt] = *(const v8bf*)(Bs + (nt * 32 + l31) * 64 + off);
#pragma unroll
      for (int mt = 0; mt < 2; ++mt)
#pragma unroll
        for (int nt = 0; nt < NT; ++nt)
          acc[mt][nt] = __builtin_amdgcn_mfma_f32_32x32x16_bf16(af[mt], bfr[nt], acc[mt][nt], 0, 0, 0);
    }
    __syncthreads();
  }

#pragma unroll
  for (int mt = 0; mt < 2; ++mt) {
#pragma unroll
    for (int nt = 0; nt < NT; ++nt) {
      int col = bn + nt * 32 + l31;
      float bb = bias ? bias[col] : 0.0f;
#pragma unroll
      for (int g = 0; g < 4; ++g) {
        int row0 = bm + w * 64 + mt * 32 + g * 8 + kc * 4;
#pragma unroll
        for (int r = 0; r < 4; ++r) {
          float val = acc[mt][nt][g * 4 + r] + bb;
          if (RELU) val = fmaxf(val, 0.0f);
          if (TROUT) C[(size_t)col * ldc + (row0 + r)] = (OutT)val;
          else       C[(size_t)(row0 + r) * ldc + col] = (OutT)val;
        }
      }
    }
  }
}

// ---------------- GEMM4: out = P @ V via split-K, 32x32x16 ----------------
// 256-thread blocks (2x2 waves of 64x64), tile 128x128, BK=64, split-K=2.
// XCD-locality swizzle: linear id -> m = id&31, n = id>>5 so id%8 = m%8 and
// all 8 N-blocks sharing an A(P) stripe land on ONE XCD (A fetched once,
// 4 MB B half-slice fits per-XCD L2). Predicted FETCH 136 -> ~70 MB.
__global__ __launch_bounds__(256, 4) void gemm4_split(const bh* __restrict__ A,
                                                      const bh* __restrict__ BT,
                                                      float* __restrict__ C0,
                                                      float* __restrict__ C1) {
  __shared__ bh As[128 * 64];          // 16 KB
  __shared__ bh Bs[128 * 64];          // 16 KB
  const int t = threadIdx.x;
  const int id = blockIdx.x;           // 0..255
  const int bm = (id & 31) * 128, bn = (id >> 5) * 128;
  const int kbeg = blockIdx.y * (TOK / 2);

  const int sr = t >> 3;               // 0..31
  const int c8 = ((t & 7) ^ (sr & 7)) * 8;
  const bh* gA = A + (size_t)(bm + sr) * TOK + kbeg + c8;
  const bh* gB = BT + (size_t)(bn + sr) * TOK + kbeg + c8;
  bh* sA = As + t * 8;
  bh* sB = Bs + t * 8;

  const int lane = t & 63, w = t >> 6;
  const int wm = (w >> 1) * 64, wn = (w & 1) * 64;
  const int l31 = lane & 31, kc = lane >> 5;

  v16f acc[2][2] = {};
  for (int k0 = 0; k0 < TOK / 2; k0 += 64) {
#pragma unroll
    for (int j = 0; j < 4; ++j) {
      gl_lds16(gA + k0 + (size_t)(j * 32) * TOK, sA + j * 2048);
      gl_lds16(gB + k0 + (size_t)(j * 32) * TOK, sB + j * 2048);
    }
    __syncthreads();
#pragma unroll
    for (int ks = 0; ks < 4; ++ks) {
      const int off = ((ks * 2 + kc) ^ (l31 & 7)) * 8;
      v8bf af[2], bfr[2];
#pragma unroll
      for (int mt = 0; mt < 2; ++mt)
        af[mt] = *(const v8bf*)(As + (wm + mt * 32 + l31) * 64 + off);
#pragma unroll
      for (int nt = 0; nt < 2; ++nt)
        bfr[nt] = *(const v8bf*)(Bs + (wn + nt * 32 + l31) * 64 + off);
#pragma unroll
      for (int mt = 0; mt < 2; ++mt)
#pragma unroll
        for (int nt = 0; nt < 2; ++nt)
          acc[mt][nt] = __builtin_amdgcn_mfma_f32_32x32x16_bf16(af[mt], bfr[nt], acc[mt][nt], 0, 0, 0);
    }
    __syncthreads();
  }

  float* C = blockIdx.y ? C1 : C0;
#pragma unroll
  for (int mt = 0; mt < 2; ++mt) {
#pragma unroll
    for (int nt = 0; nt < 2; ++nt) {
      int col = bn + wn + nt * 32 + l31;
#pragma unroll
      for (int g = 0; g < 4; ++g) {
        int row0 = bm + wm + mt * 32 + g * 8 + kc * 4;
#pragma unroll
        for (int r = 0; r < 4; ++r)
          C[(size_t)(row0 + r) * DIM + col] = acc[mt][nt][g * 4 + r];
      }
    }
  }
}

// ---------------- out += partial (float4) ----------------------------------
__global__ __launch_bounds__(256) void add_partial(float* __restrict__ out,
                                                   const float* __restrict__ part) {
  size_t i = ((size_t)blockIdx.x * 256 + threadIdx.x) * 4;
  float4 a = *(const float4*)(out + i);
  float4 b = *(const float4*)(part + i);
  a.x += b.x; a.y += b.y; a.z += b.z; a.w += b.w;
  *(float4*)(out + i) = a;
}

// ---------------- row softmax in place on bf16 (TOK cols) ----------------
__global__ __launch_bounds__(256) void softmax_inplace(bh* __restrict__ P) {
  int row = blockIdx.x;
  bh* p = P + (size_t)row * TOK;
  int t = threadIdx.x;
  v8bf c0 = *(v8bf*)(p + t * 16);
  v8bf c1 = *(v8bf*)(p + t * 16 + 8);
  float v[16];
#pragma unroll
  for (int i = 0; i < 8; ++i) { v[i] = (float)c0[i]; v[8 + i] = (float)c1[i]; }
  float m = v[0];
#pragma unroll
  for (int i = 1; i < 16; ++i) m = fmaxf(m, v[i]);
#pragma unroll
  for (int off = 32; off > 0; off >>= 1) m = fmaxf(m, __shfl_xor(m, off));
  __shared__ float redm[4], reds[4];
  int lane = t & 63, w = t >> 6;
  if (lane == 0) redm[w] = m;
  __syncthreads();
  m = fmaxf(fmaxf(redm[0], redm[1]), fmaxf(redm[2], redm[3]));
  float s = 0.f;
#pragma unroll
  for (int i = 0; i < 16; ++i) { v[i] = __expf(v[i] - m); s += v[i]; }
#pragma unroll
  for (int off = 32; off > 0; off >>= 1) s += __shfl_xor(s, off);
  if (lane == 0) reds[w] = s;
  __syncthreads();
  s = reds[0] + reds[1] + reds[2] + reds[3];
  float inv = 1.0f / s;
#pragma unroll
  for (int i = 0; i < 8; ++i) { c0[i] = (bh)(v[i] * inv); c1[i] = (bh)(v[8 + i] * inv); }
  *(v8bf*)(p + t * 16) = c0;
  *(v8bf*)(p + t * 16 + 8) = c1;
}

extern "C" void kernel_launch(void* const* d_in, const int* in_sizes, int n_in,
                              void* d_out, int out_size, void* d_ws, size_t ws_size,
                              hipStream_t stream) {
  (void)in_sizes; (void)n_in; (void)out_size; (void)ws_size;
  const float* X  = (const float*)d_in[0];
  // d_in[1] = mask, unused by the module
  const float* Wv = (const float*)d_in[2];
  const float* bv = (const float*)d_in[3];
  const float* W1 = (const float*)d_in[4];
  const float* b1 = (const float*)d_in[5];
  const float* W2 = (const float*)d_in[6];
  const float* b2 = (const float*)d_in[7];
  float* out = (float*)d_out;

  char* ws = (char*)d_ws;
  bh* featb = (bh*)(ws);                       // 4096 x 2048 bf16 : 16 MiB
  bh* WvT   = (bh*)(ws + (16u << 20));         // 1024 x 1024      :  2 MiB
  bh* W1T   = (bh*)(ws + (18u << 20));         // 2048 x 2048      :  8 MiB
  bh* W2T   = (bh*)(ws + (26u << 20));         // 4096 x 2048      : 16 MiB
  bh* Vt    = (bh*)(ws + (42u << 20));         // 1024 x 4096      :  8 MiB
  bh* hid   = (bh*)(ws + (50u << 20));         // 4096 x 2048      : 16 MiB
  bh* scr   = (bh*)(ws + (66u << 20));         // 4096 x 4096      : 32 MiB
  float* S  = (float*)(ws + (98u << 20));      // 1024 fp32
  // GEMM4 split-K partial reuses the W2T region (dead after GEMM3): 16 MiB fp32
  float* part1 = (float*)(ws + (26u << 20));

  hipError_t e = hipMemsetAsync(S, 0, DIM * sizeof(float), stream);
  (void)e;
  prep_x_colsum<<<dim3(DIM / 512, TOK / 16), 256, 0, stream>>>(X, featb, S);
  prep_loo<<<dim3((TOK * DIM) / 1024), 256, 0, stream>>>(X, S, featb);
  transpose_all<<<dim3(1024 + 4096 + 8192), dim3(32, 8), 0, stream>>>(
      Wv, W1, W2, WvT, W1T, W2T);

  // V^T = (feat_left @ Wv + bv)^T  -> Vt (1024 x 4096, ld 4096)
  gemm_bt<64, false, true, bh><<<dim3(DIM / 64, TOK / 128), 128, 0, stream>>>(
      featb, WvT, bv, Vt, DIM, 2 * DIM, DIM, TOK);
  // hid = relu(feat @ W1 + b1)
  gemm_bt<128, true, false, bh><<<dim3(HID / 128, TOK / 128), 128, 0, stream>>>(
      featb, W1T, b1, hid, 2 * DIM, 2 * DIM, 2 * DIM, HID);
  // scr = hid @ W2 + b2
  gemm_bt<128, false, false, bh><<<dim3(TOK / 128, TOK / 128), 128, 0, stream>>>(
      hid, W2T, b2, scr, HID, HID, HID, TOK);
  softmax_inplace<<<dim3(TOK), 256, 0, stream>>>(scr);
  // out = softmax(scr) @ V — split-K=2, k0 -> out, k1 -> part1, then reduce
  gemm4_split<<<dim3(256, 2), 256, 0, stream>>>(scr, Vt, out, part1);
  add_partial<<<dim3((TOK * DIM) / 1024), 256, 0, stream>>>(out, part1);
}

// Round 8
// 332.097 us; speedup vs baseline: 1.0712x; 1.0712x over previous
//
#include <hip/hip_runtime.h>
#include <hip/hip_bf16.h>

#define TOK 4096
#define DIM 1024
#define HID 2048
#define LN10K 9.210340371976184f

typedef __bf16 bh;
typedef __bf16 v8bf __attribute__((ext_vector_type(8)));
typedef float v4f __attribute__((ext_vector_type(4)));

typedef const __attribute__((address_space(1))) void* gvp;
typedef __attribute__((address_space(3))) void* svp;

__device__ __forceinline__ void gl_lds16(const bh* g, bh* s) {
  __builtin_amdgcn_global_load_lds((gvp)g, (svp)s, 16, 0, 0);
}

// ---------------- prep: cast X -> feat left half, colsum(E) ----------------
__global__ __launch_bounds__(256) void prep_x_colsum(const float* __restrict__ X,
                                                     bh* __restrict__ featb,
                                                     float* __restrict__ S) {
  int cp = blockIdx.x * 256 + threadIdx.x;      // column pair 0..511
  int c = cp * 2;
  int r0 = blockIdx.y * 16;
  float inv_denom = __expf(-(float)c * (LN10K / (float)DIM));
  float s0 = 0.f, s1 = 0.f;
#pragma unroll 4
  for (int r = r0; r < r0 + 16; ++r) {
    float2 x = *(const float2*)(X + (size_t)r * DIM + c);
    float sn, cs;
    __sincosf((float)r * inv_denom, &sn, &cs);
    s0 += sn * x.x;
    s1 += cs * x.y;
    bh pair[2] = {(bh)x.x, (bh)x.y};
    *(ushort2*)(featb + (size_t)r * (2 * DIM) + c) = *(ushort2*)pair;
  }
  atomicAdd(&S[c], s0);
  atomicAdd(&S[c + 1], s1);
}

// ---------------- prep: loo -> feat right half ----------------
__global__ __launch_bounds__(256) void prep_loo(const float* __restrict__ X,
                                                const float* __restrict__ S,
                                                bh* __restrict__ featb) {
  size_t e4 = ((size_t)blockIdx.x * 256 + threadIdx.x) * 4;  // over TOK*DIM
  int r = (int)(e4 >> 10);
  int c = (int)(e4 & 1023);
  float4 x = *(const float4*)(X + e4);
  float4 s = *(const float4*)(S + c);
  float id0 = __expf(-(float)c * (LN10K / (float)DIM));
  float id1 = __expf(-(float)(c + 2) * (LN10K / (float)DIM));
  float sn0, cs0, sn1, cs1;
  __sincosf((float)r * id0, &sn0, &cs0);
  __sincosf((float)r * id1, &sn1, &cs1);
  const float inv = 1.0f / (float)(TOK - 1);
  bh outv[4];
  outv[0] = (bh)((s.x - sn0 * x.x) * inv);
  outv[1] = (bh)((s.y - cs0 * x.y) * inv);
  outv[2] = (bh)((s.z - sn1 * x.z) * inv);
  outv[3] = (bh)((s.w - cs1 * x.w) * inv);
  *(ushort4*)(featb + (size_t)r * (2 * DIM) + DIM + c) = *(ushort4*)outv;
}

// ---------------- fused transpose+cast of all 3 weights (1 dispatch) -------
__global__ __launch_bounds__(256) void transpose_all(const float* __restrict__ Wv,
                                                     const float* __restrict__ W1,
                                                     const float* __restrict__ W2,
                                                     bh* __restrict__ WvT,
                                                     bh* __restrict__ W1T,
                                                     bh* __restrict__ W2T) {
  __shared__ float tile[32][33];
  int bid = blockIdx.x;
  const float* in; bh* out; int Ncol, R, bx, by;
  if (bid < 1024)      { in = Wv; out = WvT; Ncol = DIM; R = DIM;
                         bx = bid & 31; by = bid >> 5; }
  else if (bid < 5120) { int b = bid - 1024; in = W1; out = W1T; Ncol = HID; R = 2 * DIM;
                         bx = b & 63; by = b >> 6; }
  else                 { int b = bid - 5120; in = W2; out = W2T; Ncol = TOK; R = HID;
                         bx = b & 127; by = b >> 7; }
  int nb = bx * 32, rb = by * 32;
  int tx = threadIdx.x, ty = threadIdx.y;  // block (32,8)
#pragma unroll
  for (int j = 0; j < 32; j += 8)
    tile[ty + j][tx] = in[(size_t)(rb + ty + j) * Ncol + nb + tx];
  __syncthreads();
#pragma unroll
  for (int j = 0; j < 32; j += 8)
    out[(size_t)(nb + ty + j) * R + rb + tx] = (bh)tile[tx][ty + j];
}

// ---------------- GEMM: C = act(A @ BT^T + bias), 16x16x32 MFMA ------------
// 128-thread blocks (2 waves), block tile 128 x BN, BK=64, wave tile 64 x BN.
// Staging: global_load_lds w=16, lane-linear LDS, 16B-grain XOR swizzle row&7
// (0 conflicts measured; 32x32x16 variant measured 4 cyc/read conflicts +
// no matrix-pipe gain — do NOT switch shapes).
// XCD-locality: linear grid, bm = (id&31)*128 -> blocks sharing an A-stripe
// have id%8 = bm%8 = same XCD -> A fetched once per XCD (2 MB in 4 MB L2).
template <int BN, bool RELU, bool TROUT, typename OutT>
__global__ __launch_bounds__(128, 2) void gemm_bt(const bh* __restrict__ A,
                                                  const bh* __restrict__ BT,
                                                  const float* __restrict__ bias,
                                                  OutT* __restrict__ C,
                                                  int K, int lda, int ldbt, int ldc) {
  constexpr int NT = BN / 16;          // 8 (BN=128) or 4 (BN=64)
  __shared__ bh As[128 * 64];          // 16 KB
  __shared__ bh Bs[BN * 64];           // 16 or 8 KB
  const int t = threadIdx.x;
  const int id = blockIdx.x;
  const int bm = (id & 31) * 128, bn = (id >> 5) * BN;

  const int sr = t >> 3;               // staging row-in-group
  const int c8 = ((t & 7) ^ (sr & 7)) * 8;
  const bh* gA = A + (size_t)(bm + sr) * lda + c8;
  const bh* gB = BT + (size_t)(bn + sr) * ldbt + c8;
  bh* sA = As + t * 8;
  bh* sB = Bs + t * 8;

  const int lane = t & 63, w = t >> 6;
  const int lc = lane & 15, q = lane >> 4;

  v4f acc[4][NT] = {};
  for (int k0 = 0; k0 < K; k0 += 64) {
#pragma unroll
    for (int j = 0; j < 8; ++j)
      gl_lds16(gA + k0 + j * 16 * lda, sA + j * 1024);
#pragma unroll
    for (int j = 0; j < NT; ++j)
      gl_lds16(gB + k0 + j * 16 * ldbt, sB + j * 1024);
    __syncthreads();
#pragma unroll
    for (int h = 0; h < 2; ++h) {
      const int off = ((h * 4 + q) ^ (lc & 7)) * 8;
      v8bf af[4], bfr[NT];
#pragma unroll
      for (int mt = 0; mt < 4; ++mt)
        af[mt] = *(const v8bf*)(As + (w * 64 + mt * 16 + lc) * 64 + off);
#pragma unroll
      for (int nt = 0; nt < NT; ++nt)
        bfr[nt] = *(const v8bf*)(Bs + (nt * 16 + lc) * 64 + off);
#pragma unroll
      for (int mt = 0; mt < 4; ++mt)
#pragma unroll
        for (int nt = 0; nt < NT; ++nt)
          acc[mt][nt] = __builtin_amdgcn_mfma_f32_16x16x32_bf16(af[mt], bfr[nt], acc[mt][nt], 0, 0, 0);
    }
    __syncthreads();
  }

  const int r4 = q * 4;
#pragma unroll
  for (int mt = 0; mt < 4; ++mt) {
    int row0 = bm + w * 64 + mt * 16 + r4;
#pragma unroll
    for (int nt = 0; nt < NT; ++nt) {
      int col = bn + nt * 16 + lc;
      float bb = bias ? bias[col] : 0.0f;
#pragma unroll
      for (int r = 0; r < 4; ++r) {
        float val = acc[mt][nt][r] + bb;
        if (RELU) val = fmaxf(val, 0.0f);
        if (TROUT) C[(size_t)col * ldc + (row0 + r)] = (OutT)val;
        else       C[(size_t)(row0 + r) * ldc + col] = (OutT)val;
      }
    }
  }
}

// ---------------- GEMM4: out = P @ V via split-K, 16x16x32 ----------------
// 256-thread blocks (2x2 waves of 64x64), tile 128x128, BK=64, split-K=2.
// XCD swizzle: bm = (id&31)*128 -> 8 N-blocks per A(P)-stripe on one XCD.
__global__ __launch_bounds__(256, 4) void gemm4_split(const bh* __restrict__ A,
                                                      const bh* __restrict__ BT,
                                                      float* __restrict__ C0,
                                                      float* __restrict__ C1) {
  __shared__ bh As[128 * 64];          // 16 KB
  __shared__ bh Bs[128 * 64];          // 16 KB
  const int t = threadIdx.x;
  const int id = blockIdx.x;           // 0..255
  const int bm = (id & 31) * 128, bn = (id >> 5) * 128;
  const int kbeg = blockIdx.y * (TOK / 2);

  const int sr = t >> 3;               // 0..31
  const int c8 = ((t & 7) ^ (sr & 7)) * 8;
  const bh* gA = A + (size_t)(bm + sr) * TOK + kbeg + c8;
  const bh* gB = BT + (size_t)(bn + sr) * TOK + kbeg + c8;
  bh* sA = As + t * 8;
  bh* sB = Bs + t * 8;

  const int lane = t & 63, w = t >> 6;
  const int wm = (w >> 1) * 64, wn = (w & 1) * 64;
  const int lc = lane & 15, q = lane >> 4;

  v4f acc[4][4] = {};
  for (int k0 = 0; k0 < TOK / 2; k0 += 64) {
#pragma unroll
    for (int j = 0; j < 4; ++j) {
      gl_lds16(gA + k0 + (size_t)(j * 32) * TOK, sA + j * 2048);
      gl_lds16(gB + k0 + (size_t)(j * 32) * TOK, sB + j * 2048);
    }
    __syncthreads();
#pragma unroll
    for (int h = 0; h < 2; ++h) {
      const int off = ((h * 4 + q) ^ (lc & 7)) * 8;
      v8bf af[4], bfr[4];
#pragma unroll
      for (int mt = 0; mt < 4; ++mt)
        af[mt] = *(const v8bf*)(As + (wm + mt * 16 + lc) * 64 + off);
#pragma unroll
      for (int nt = 0; nt < 4; ++nt)
        bfr[nt] = *(const v8bf*)(Bs + (wn + nt * 16 + lc) * 64 + off);
#pragma unroll
      for (int mt = 0; mt < 4; ++mt)
#pragma unroll
        for (int nt = 0; nt < 4; ++nt)
          acc[mt][nt] = __builtin_amdgcn_mfma_f32_16x16x32_bf16(af[mt], bfr[nt], acc[mt][nt], 0, 0, 0);
    }
    __syncthreads();
  }

  float* C = blockIdx.y ? C1 : C0;
  const int r4 = q * 4;
#pragma unroll
  for (int mt = 0; mt < 4; ++mt) {
    int row0 = bm + wm + mt * 16 + r4;
#pragma unroll
    for (int nt = 0; nt < 4; ++nt) {
      int col = bn + wn + nt * 16 + lc;
#pragma unroll
      for (int r = 0; r < 4; ++r)
        C[(size_t)(row0 + r) * DIM + col] = acc[mt][nt][r];
    }
  }
}

// ---------------- out += partial (float4) ----------------------------------
__global__ __launch_bounds__(256) void add_partial(float* __restrict__ out,
                                                   const float* __restrict__ part) {
  size_t i = ((size_t)blockIdx.x * 256 + threadIdx.x) * 4;
  float4 a = *(const float4*)(out + i);
  float4 b = *(const float4*)(part + i);
  a.x += b.x; a.y += b.y; a.z += b.z; a.w += b.w;
  *(float4*)(out + i) = a;
}

// ---------------- row softmax in place on bf16 (TOK cols) ----------------
__global__ __launch_bounds__(256) void softmax_inplace(bh* __restrict__ P) {
  int row = blockIdx.x;
  bh* p = P + (size_t)row * TOK;
  int t = threadIdx.x;
  v8bf c0 = *(v8bf*)(p + t * 16);
  v8bf c1 = *(v8bf*)(p + t * 16 + 8);
  float v[16];
#pragma unroll
  for (int i = 0; i < 8; ++i) { v[i] = (float)c0[i]; v[8 + i] = (float)c1[i]; }
  float m = v[0];
#pragma unroll
  for (int i = 1; i < 16; ++i) m = fmaxf(m, v[i]);
#pragma unroll
  for (int off = 32; off > 0; off >>= 1) m = fmaxf(m, __shfl_xor(m, off));
  __shared__ float redm[4], reds[4];
  int lane = t & 63, w = t >> 6;
  if (lane == 0) redm[w] = m;
  __syncthreads();
  m = fmaxf(fmaxf(redm[0], redm[1]), fmaxf(redm[2], redm[3]));
  float s = 0.f;
#pragma unroll
  for (int i = 0; i < 16; ++i) { v[i] = __expf(v[i] - m); s += v[i]; }
#pragma unroll
  for (int off = 32; off > 0; off >>= 1) s += __shfl_xor(s, off);
  if (lane == 0) reds[w] = s;
  __syncthreads();
  s = reds[0] + reds[1] + reds[2] + reds[3];
  float inv = 1.0f / s;
#pragma unroll
  for (int i = 0; i < 8; ++i) { c0[i] = (bh)(v[i] * inv); c1[i] = (bh)(v[8 + i] * inv); }
  *(v8bf*)(p + t * 16) = c0;
  *(v8bf*)(p + t * 16 + 8) = c1;
}

extern "C" void kernel_launch(void* const* d_in, const int* in_sizes, int n_in,
                              void* d_out, int out_size, void* d_ws, size_t ws_size,
                              hipStream_t stream) {
  (void)in_sizes; (void)n_in; (void)out_size; (void)ws_size;
  const float* X  = (const float*)d_in[0];
  // d_in[1] = mask, unused by the module
  const float* Wv = (const float*)d_in[2];
  const float* bv = (const float*)d_in[3];
  const float* W1 = (const float*)d_in[4];
  const float* b1 = (const float*)d_in[5];
  const float* W2 = (const float*)d_in[6];
  const float* b2 = (const float*)d_in[7];
  float* out = (float*)d_out;

  char* ws = (char*)d_ws;
  bh* featb = (bh*)(ws);                       // 4096 x 2048 bf16 : 16 MiB
  bh* WvT   = (bh*)(ws + (16u << 20));         // 1024 x 1024      :  2 MiB
  bh* W1T   = (bh*)(ws + (18u << 20));         // 2048 x 2048      :  8 MiB
  bh* W2T   = (bh*)(ws + (26u << 20));         // 4096 x 2048      : 16 MiB
  bh* Vt    = (bh*)(ws + (42u << 20));         // 1024 x 4096      :  8 MiB
  bh* hid   = (bh*)(ws + (50u << 20));         // 4096 x 2048      : 16 MiB
  bh* scr   = (bh*)(ws + (66u << 20));         // 4096 x 4096      : 32 MiB
  float* S  = (float*)(ws + (98u << 20));      // 1024 fp32
  // GEMM4 split-K partial reuses the W2T region (dead after GEMM3): 16 MiB fp32
  float* part1 = (float*)(ws + (26u << 20));

  hipError_t e = hipMemsetAsync(S, 0, DIM * sizeof(float), stream);
  (void)e;
  prep_x_colsum<<<dim3(DIM / 512, TOK / 16), 256, 0, stream>>>(X, featb, S);
  prep_loo<<<dim3((TOK * DIM) / 1024), 256, 0, stream>>>(X, S, featb);
  transpose_all<<<dim3(1024 + 4096 + 8192), dim3(32, 8), 0, stream>>>(
      Wv, W1, W2, WvT, W1T, W2T);

  // V^T = (feat_left @ Wv + bv)^T  -> Vt (1024 x 4096, ld 4096)
  gemm_bt<64, false, true, bh><<<dim3(32 * (DIM / 64)), 128, 0, stream>>>(
      featb, WvT, bv, Vt, DIM, 2 * DIM, DIM, TOK);
  // hid = relu(feat @ W1 + b1)
  gemm_bt<128, true, false, bh><<<dim3(32 * (HID / 128)), 128, 0, stream>>>(
      featb, W1T, b1, hid, 2 * DIM, 2 * DIM, 2 * DIM, HID);
  // scr = hid @ W2 + b2
  gemm_bt<128, false, false, bh><<<dim3(32 * (TOK / 128)), 128, 0, stream>>>(
      hid, W2T, b2, scr, HID, HID, HID, TOK);
  softmax_inplace<<<dim3(TOK), 256, 0, stream>>>(scr);
  // out = softmax(scr) @ V — split-K=2, k0 -> out, k1 -> part1, then reduce
  gemm4_split<<<dim3(256, 2), 256, 0, stream>>>(scr, Vt, out, part1);
  add_partial<<<dim3((TOK * DIM) / 1024), 256, 0, stream>>>(out, part1);
}

// Round 9
// 323.447 us; speedup vs baseline: 1.0998x; 1.0267x over previous
//
#include <hip/hip_runtime.h>
#include <hip/hip_bf16.h>

#define TOK 4096
#define DIM 1024
#define HID 2048
#define LN10K 9.210340371976184f

typedef __bf16 bh;
typedef __bf16 v8bf __attribute__((ext_vector_type(8)));
typedef float v4f __attribute__((ext_vector_type(4)));

typedef const __attribute__((address_space(1))) void* gvp;
typedef __attribute__((address_space(3))) void* svp;

__device__ __forceinline__ void gl_lds16(const bh* g, bh* s) {
  __builtin_amdgcn_global_load_lds((gvp)g, (svp)s, 16, 0, 0);
}

// ---------------- prep: cast X -> feat left half, colsum(E) ----------------
__global__ __launch_bounds__(256) void prep_x_colsum(const float* __restrict__ X,
                                                     bh* __restrict__ featb,
                                                     float* __restrict__ S) {
  int cp = blockIdx.x * 256 + threadIdx.x;      // column pair 0..511
  int c = cp * 2;
  int r0 = blockIdx.y * 16;
  float inv_denom = __expf(-(float)c * (LN10K / (float)DIM));
  float s0 = 0.f, s1 = 0.f;
#pragma unroll 4
  for (int r = r0; r < r0 + 16; ++r) {
    float2 x = *(const float2*)(X + (size_t)r * DIM + c);
    float sn, cs;
    __sincosf((float)r * inv_denom, &sn, &cs);
    s0 += sn * x.x;
    s1 += cs * x.y;
    bh pair[2] = {(bh)x.x, (bh)x.y};
    *(ushort2*)(featb + (size_t)r * (2 * DIM) + c) = *(ushort2*)pair;
  }
  atomicAdd(&S[c], s0);
  atomicAdd(&S[c + 1], s1);
}

// ---------------- prep: loo -> feat right half ----------------
__global__ __launch_bounds__(256) void prep_loo(const float* __restrict__ X,
                                                const float* __restrict__ S,
                                                bh* __restrict__ featb) {
  size_t e4 = ((size_t)blockIdx.x * 256 + threadIdx.x) * 4;  // over TOK*DIM
  int r = (int)(e4 >> 10);
  int c = (int)(e4 & 1023);
  float4 x = *(const float4*)(X + e4);
  float4 s = *(const float4*)(S + c);
  float id0 = __expf(-(float)c * (LN10K / (float)DIM));
  float id1 = __expf(-(float)(c + 2) * (LN10K / (float)DIM));
  float sn0, cs0, sn1, cs1;
  __sincosf((float)r * id0, &sn0, &cs0);
  __sincosf((float)r * id1, &sn1, &cs1);
  const float inv = 1.0f / (float)(TOK - 1);
  bh outv[4];
  outv[0] = (bh)((s.x - sn0 * x.x) * inv);
  outv[1] = (bh)((s.y - cs0 * x.y) * inv);
  outv[2] = (bh)((s.z - sn1 * x.z) * inv);
  outv[3] = (bh)((s.w - cs1 * x.w) * inv);
  *(ushort4*)(featb + (size_t)r * (2 * DIM) + DIM + c) = *(ushort4*)outv;
}

// ---------------- fused transpose+cast of all 3 weights (1 dispatch) -------
__global__ __launch_bounds__(256) void transpose_all(const float* __restrict__ Wv,
                                                     const float* __restrict__ W1,
                                                     const float* __restrict__ W2,
                                                     bh* __restrict__ WvT,
                                                     bh* __restrict__ W1T,
                                                     bh* __restrict__ W2T) {
  __shared__ float tile[32][33];
  int bid = blockIdx.x;
  const float* in; bh* out; int Ncol, R, bx, by;
  if (bid < 1024)      { in = Wv; out = WvT; Ncol = DIM; R = DIM;
                         bx = bid & 31; by = bid >> 5; }
  else if (bid < 5120) { int b = bid - 1024; in = W1; out = W1T; Ncol = HID; R = 2 * DIM;
                         bx = b & 63; by = b >> 6; }
  else                 { int b = bid - 5120; in = W2; out = W2T; Ncol = TOK; R = HID;
                         bx = b & 127; by = b >> 7; }
  int nb = bx * 32, rb = by * 32;
  int tx = threadIdx.x, ty = threadIdx.y;  // block (32,8)
#pragma unroll
  for (int j = 0; j < 32; j += 8)
    tile[ty + j][tx] = in[(size_t)(rb + ty + j) * Ncol + nb + tx];
  __syncthreads();
#pragma unroll
  for (int j = 0; j < 32; j += 8)
    out[(size_t)(nb + ty + j) * R + rb + tx] = (bh)tile[tx][ty + j];
}

// ---------------- GEMM: C = act(A @ BT^T + bias), 16x16x32 MFMA ------------
// 128-thread blocks (2 waves), block tile 128 x BN, BK=64, wave tile 64 x BN.
// Staging: global_load_lds w=16, lane-linear LDS, 16B-grain XOR swizzle row&7
// (0 conflicts measured; 32x32x16 shape measured WORSE — conflicts + no gain).
// EXPS: epilogue stores exp(score) (no max-subtraction: |score| <~ 4, safe)
// and atomically accumulates fp32 row sums -> softmax normalization happens
// in the consumer's epilogue; the standalone softmax kernel is eliminated.
template <int BN, bool RELU, bool TROUT, bool EXPS, typename OutT>
__global__ __launch_bounds__(128, 2) void gemm_bt(const bh* __restrict__ A,
                                                  const bh* __restrict__ BT,
                                                  const float* __restrict__ bias,
                                                  OutT* __restrict__ C,
                                                  float* __restrict__ rowsum,
                                                  int K, int lda, int ldbt, int ldc) {
  constexpr int NT = BN / 16;          // 8 (BN=128) or 4 (BN=64)
  __shared__ bh As[128 * 64];          // 16 KB
  __shared__ bh Bs[BN * 64];           // 16 or 8 KB
  const int t = threadIdx.x;
  const int id = blockIdx.x;
  const int bm = (id & 31) * 128, bn = (id >> 5) * BN;

  const int sr = t >> 3;               // staging row-in-group
  const int c8 = ((t & 7) ^ (sr & 7)) * 8;
  const bh* gA = A + (size_t)(bm + sr) * lda + c8;
  const bh* gB = BT + (size_t)(bn + sr) * ldbt + c8;
  bh* sA = As + t * 8;
  bh* sB = Bs + t * 8;

  const int lane = t & 63, w = t >> 6;
  const int lc = lane & 15, q = lane >> 4;

  v4f acc[4][NT] = {};
  for (int k0 = 0; k0 < K; k0 += 64) {
#pragma unroll
    for (int j = 0; j < 8; ++j)
      gl_lds16(gA + k0 + j * 16 * lda, sA + j * 1024);
#pragma unroll
    for (int j = 0; j < NT; ++j)
      gl_lds16(gB + k0 + j * 16 * ldbt, sB + j * 1024);
    __syncthreads();
#pragma unroll
    for (int h = 0; h < 2; ++h) {
      const int off = ((h * 4 + q) ^ (lc & 7)) * 8;
      v8bf af[4], bfr[NT];
#pragma unroll
      for (int mt = 0; mt < 4; ++mt)
        af[mt] = *(const v8bf*)(As + (w * 64 + mt * 16 + lc) * 64 + off);
#pragma unroll
      for (int nt = 0; nt < NT; ++nt)
        bfr[nt] = *(const v8bf*)(Bs + (nt * 16 + lc) * 64 + off);
#pragma unroll
      for (int mt = 0; mt < 4; ++mt)
#pragma unroll
        for (int nt = 0; nt < NT; ++nt)
          acc[mt][nt] = __builtin_amdgcn_mfma_f32_16x16x32_bf16(af[mt], bfr[nt], acc[mt][nt], 0, 0, 0);
    }
    __syncthreads();
  }

  // C/D layout: col = lane&15, row = q*4 + r  (m89-verified)
  const int r4 = q * 4;
  if (EXPS) {
    float bbv[NT];
#pragma unroll
    for (int nt = 0; nt < NT; ++nt) bbv[nt] = bias ? bias[bn + nt * 16 + lc] : 0.0f;
#pragma unroll
    for (int mt = 0; mt < 4; ++mt) {
#pragma unroll
      for (int r = 0; r < 4; ++r) {
        int row = bm + w * 64 + mt * 16 + r4 + r;
        float rs = 0.0f;
#pragma unroll
        for (int nt = 0; nt < NT; ++nt) {
          float val = __expf(acc[mt][nt][r] + bbv[nt]);
          rs += val;
          C[(size_t)row * ldc + bn + nt * 16 + lc] = (OutT)val;
        }
        rs += __shfl_xor(rs, 1);
        rs += __shfl_xor(rs, 2);
        rs += __shfl_xor(rs, 4);
        rs += __shfl_xor(rs, 8);
        if (lc == 0) atomicAdd(rowsum + row, rs);
      }
    }
  } else {
#pragma unroll
    for (int mt = 0; mt < 4; ++mt) {
      int row0 = bm + w * 64 + mt * 16 + r4;
#pragma unroll
      for (int nt = 0; nt < NT; ++nt) {
        int col = bn + nt * 16 + lc;
        float bb = bias ? bias[col] : 0.0f;
#pragma unroll
        for (int r = 0; r < 4; ++r) {
          float val = acc[mt][nt][r] + bb;
          if (RELU) val = fmaxf(val, 0.0f);
          if (TROUT) C[(size_t)col * ldc + (row0 + r)] = (OutT)val;
          else       C[(size_t)(row0 + r) * ldc + col] = (OutT)val;
        }
      }
    }
  }
}

// ---------------- GEMM4: part = expP @ V via split-K, 16x16x32 -------------
// 256-thread blocks (2x2 waves of 64x64), tile 128x128, BK=64, split-K=2.
__global__ __launch_bounds__(256, 4) void gemm4_split(const bh* __restrict__ A,
                                                      const bh* __restrict__ BT,
                                                      float* __restrict__ C0,
                                                      float* __restrict__ C1) {
  __shared__ bh As[128 * 64];          // 16 KB
  __shared__ bh Bs[128 * 64];          // 16 KB
  const int t = threadIdx.x;
  const int id = blockIdx.x;           // 0..255
  const int bm = (id & 31) * 128, bn = (id >> 5) * 128;
  const int kbeg = blockIdx.y * (TOK / 2);

  const int sr = t >> 3;               // 0..31
  const int c8 = ((t & 7) ^ (sr & 7)) * 8;
  const bh* gA = A + (size_t)(bm + sr) * TOK + kbeg + c8;
  const bh* gB = BT + (size_t)(bn + sr) * TOK + kbeg + c8;
  bh* sA = As + t * 8;
  bh* sB = Bs + t * 8;

  const int lane = t & 63, w = t >> 6;
  const int wm = (w >> 1) * 64, wn = (w & 1) * 64;
  const int lc = lane & 15, q = lane >> 4;

  v4f acc[4][4] = {};
  for (int k0 = 0; k0 < TOK / 2; k0 += 64) {
#pragma unroll
    for (int j = 0; j < 4; ++j) {
      gl_lds16(gA + k0 + (size_t)(j * 32) * TOK, sA + j * 2048);
      gl_lds16(gB + k0 + (size_t)(j * 32) * TOK, sB + j * 2048);
    }
    __syncthreads();
#pragma unroll
    for (int h = 0; h < 2; ++h) {
      const int off = ((h * 4 + q) ^ (lc & 7)) * 8;
      v8bf af[4], bfr[4];
#pragma unroll
      for (int mt = 0; mt < 4; ++mt)
        af[mt] = *(const v8bf*)(As + (wm + mt * 16 + lc) * 64 + off);
#pragma unroll
      for (int nt = 0; nt < 4; ++nt)
        bfr[nt] = *(const v8bf*)(Bs + (wn + nt * 16 + lc) * 64 + off);
#pragma unroll
      for (int mt = 0; mt < 4; ++mt)
#pragma unroll
        for (int nt = 0; nt < 4; ++nt)
          acc[mt][nt] = __builtin_amdgcn_mfma_f32_16x16x32_bf16(af[mt], bfr[nt], acc[mt][nt], 0, 0, 0);
    }
    __syncthreads();
  }

  float* C = blockIdx.y ? C1 : C0;
  const int r4 = q * 4;
#pragma unroll
  for (int mt = 0; mt < 4; ++mt) {
    int row0 = bm + wm + mt * 16 + r4;
#pragma unroll
    for (int nt = 0; nt < 4; ++nt) {
      int col = bn + wn + nt * 16 + lc;
#pragma unroll
      for (int r = 0; r < 4; ++r)
        C[(size_t)(row0 + r) * DIM + col] = acc[mt][nt][r];
    }
  }
}

// ---------------- finalize: out = (p0 + p1) / rowsum[row] ------------------
__global__ __launch_bounds__(256) void finalize(const float* __restrict__ p0,
                                                const float* __restrict__ p1,
                                                const float* __restrict__ rowsum,
                                                float* __restrict__ out) {
  size_t i = ((size_t)blockIdx.x * 256 + threadIdx.x) * 4;
  int row = (int)(i >> 10);            // DIM = 1024
  float inv = 1.0f / rowsum[row];
  float4 a = *(const float4*)(p0 + i);
  float4 b = *(const float4*)(p1 + i);
  float4 o;
  o.x = (a.x + b.x) * inv; o.y = (a.y + b.y) * inv;
  o.z = (a.z + b.z) * inv; o.w = (a.w + b.w) * inv;
  *(float4*)(out + i) = o;
}

extern "C" void kernel_launch(void* const* d_in, const int* in_sizes, int n_in,
                              void* d_out, int out_size, void* d_ws, size_t ws_size,
                              hipStream_t stream) {
  (void)in_sizes; (void)n_in; (void)out_size; (void)ws_size;
  const float* X  = (const float*)d_in[0];
  // d_in[1] = mask, unused by the module
  const float* Wv = (const float*)d_in[2];
  const float* bv = (const float*)d_in[3];
  const float* W1 = (const float*)d_in[4];
  const float* b1 = (const float*)d_in[5];
  const float* W2 = (const float*)d_in[6];
  const float* b2 = (const float*)d_in[7];
  float* out = (float*)d_out;

  char* ws = (char*)d_ws;
  bh* featb = (bh*)(ws);                       // 4096 x 2048 bf16 : 16 MiB
  bh* WvT   = (bh*)(ws + (16u << 20));         // 1024 x 1024      :  2 MiB
  bh* W1T   = (bh*)(ws + (18u << 20));         // 2048 x 2048      :  8 MiB
  bh* W2T   = (bh*)(ws + (26u << 20));         // 4096 x 2048      : 16 MiB
  bh* Vt    = (bh*)(ws + (42u << 20));         // 1024 x 4096      :  8 MiB
  bh* hid   = (bh*)(ws + (50u << 20));         // 4096 x 2048      : 16 MiB
  bh* scr   = (bh*)(ws + (66u << 20));         // 4096 x 4096 bf16 : 32 MiB (exp scores)
  float* S  = (float*)(ws + (98u << 20));      // 1024 fp32 (4 KB)
  float* rowsum = (float*)(ws + (98u << 20) + 4096);  // 4096 fp32 (16 KB)
  // split-K partials: part0 reuses featb region (dead after gemm2),
  // part1 reuses W2T region (dead after gemm3). 16 MiB fp32 each.
  float* part0 = (float*)(ws);
  float* part1 = (float*)(ws + (26u << 20));

  hipError_t e = hipMemsetAsync(S, 0, 4096 + 4096 * sizeof(float), stream);
  (void)e;
  prep_x_colsum<<<dim3(DIM / 512, TOK / 16), 256, 0, stream>>>(X, featb, S);
  prep_loo<<<dim3((TOK * DIM) / 1024), 256, 0, stream>>>(X, S, featb);
  transpose_all<<<dim3(1024 + 4096 + 8192), dim3(32, 8), 0, stream>>>(
      Wv, W1, W2, WvT, W1T, W2T);

  // V^T = (feat_left @ Wv + bv)^T  -> Vt (1024 x 4096, ld 4096)
  gemm_bt<64, false, true, false, bh><<<dim3(32 * (DIM / 64)), 128, 0, stream>>>(
      featb, WvT, bv, Vt, nullptr, DIM, 2 * DIM, DIM, TOK);
  // hid = relu(feat @ W1 + b1)
  gemm_bt<128, true, false, false, bh><<<dim3(32 * (HID / 128)), 128, 0, stream>>>(
      featb, W1T, b1, hid, nullptr, 2 * DIM, 2 * DIM, 2 * DIM, HID);
  // scr = exp(hid @ W2 + b2)  [unnormalized softmax numerator] + rowsum
  gemm_bt<128, false, false, true, bh><<<dim3(32 * (TOK / 128)), 128, 0, stream>>>(
      hid, W2T, b2, scr, rowsum, HID, HID, HID, TOK);
  // parts = scr @ V, split-K=2
  gemm4_split<<<dim3(256, 2), 256, 0, stream>>>(scr, Vt, part0, part1);
  // out = (part0 + part1) / rowsum
  finalize<<<dim3((TOK * DIM) / 1024), 256, 0, stream>>>(part0, part1, rowsum, out);
}